// Round 12
// baseline (106.586 us; speedup 1.0000x reference)
//
#include <hip/hip_runtime.h>

// Gabor renderer, round 12.
// r11 smoking gun: VGPR_Count=20 for a kernel that "preloads" 24 VGPRs of
// params -> the compiler sank the s_pk reads back into the loop (2x uniform
// ds_read_b128 per iter = r4's LDS-pipe-bound loop in disguise; 1583
// wave-iter/CU x 24cy = ~16us LDS serialization). Same remat pathology
// explains r9/r10 (VGPR=12, global loads in-loop) — all ~38-43us alike.
// Fix: opaque asm pin (`asm volatile("" : "+v"(x))`) on all 24 param regs
// after preload — compiler cannot remat a load past an asm that "writes"
// the value, so the loop's readlanes consume real VGPRs. Zero memory ops.
// Bonus: x-floorf(x) -> __builtin_amdgcn_fractf (v_fract_f32, bit-identical
// incl. negatives) saves 2 VALU/eval.
// Numerics otherwise byte-identical to r11 (absmax 0.0234375 expected).

constexpr double SR_D      = 24000.0;
constexpr double INV_SR_D  = 1.0 / 24000.0;
constexpr double INV_2PI_D = 0.15915494309189535;
constexpr double LOG2E_D   = 1.4426950408889634;
constexpr int    HALF_MAX  = 1201;
constexpr int    TILE      = 256;     // samples per tile
constexpr int    CAP       = 192;     // per-tile atom capacity (mean ~108, max ~160)

// broadcast lane li's value of a wave-held float register (-> SGPR)
__device__ __forceinline__ float rl(float v, int li)
{
    return __int_as_float(__builtin_amdgcn_readlane(__float_as_int(v), li));
}

__global__ __launch_bounds__(512, 8)
void gabor_one(const float* __restrict__ amp, const float* __restrict__ tau,
               const float* __restrict__ omg, const float* __restrict__ sig,
               const float* __restrict__ phi, const float* __restrict__ gam,
               float* __restrict__ out, int num_samples, int n_atoms)
{
    __shared__ int            s_cnt;
    __shared__ unsigned short s_id[CAP];
    __shared__ float4         s_pk[CAP][2];
    __shared__ float          s_part[TILE];

    const int tile0 = blockIdx.x << 8;
    const int t     = (int)threadIdx.x;
    if (t == 0) s_cnt = 0;
    __syncthreads();

    // ---- phase A: conservative overlap scan (superset of |dt|<=5sig) ----
    const float lo_s = (float)(tile0 - 3);
    const float hi_s = (float)(tile0 + TILE - 1 + 3);
    for (int a = t; a < n_atoms; a += 512) {
        float c = tau[a] * 24000.0f;
        float w = fmaf(sig[a], 120000.0f, 2.0f);     // 5*sig*SR + margin
        if (c + w >= lo_s && c - w <= hi_s) {
            int slot = atomicAdd(&s_cnt, 1);
            if (slot < CAP) s_id[slot] = (unsigned short)a;
        }
    }
    __syncthreads();
    const int cnt = min(s_cnt, CAP);

    // ---- phase B: f64 prep for listed atoms -> LDS packed params ----
    for (int i = t; i < cnt; i += 512) {
        int a = (int)s_id[i];
        double tu = (double)tau[a], om = (double)omg[a], gm = (double)gam[a];
        float  sgf = sig[a];
        float  amf = amp[a];
        int center = (int)rint(tu * SR_D);
        double q  = om * INV_SR_D;                       // [0, 1/3)
        float  qf = (float)q;
        float ohi = __uint_as_float(__float_as_uint(qf) & 0xFFFFF000u);
        float olo = (float)(q - (double)ohi);            // exact tail
        double d0 = (double)center * INV_SR_D - tu;      // f64: cancellation-safe
        double pr = om * d0 + (double)phi[a] * INV_2PI_D + 0.5 * gm * d0 * d0;
        double po = pr - floor(pr);
        if (amf < 0.0f) po += 0.5;                       // sign -> phase
        float isg2 = 1.0f / (sgf * sgf);                 // f32 IEEE div (~1e-7)
        double E2  = -0.5 * LOG2E_D * (double)isg2;      // exp2-domain coeff
        float e2p  = (float)(E2 * INV_SR_D * INV_SR_D);
        float b1   = (float)(2.0 * E2 * d0 * INV_SR_D);
        float aabs = fabsf(amf);
        float Lp   = (aabs > 0.0f)
                   ? __builtin_amdgcn_logf(aabs) + (float)(E2 * d0 * d0)
                   : -1.0e30f;                           // v_log_f32 = log2
        float gmh  = (float)(0.5 * gm * INV_SR_D * INV_SR_D);
        s_pk[i][0] = make_float4((float)center, ohi, olo, (float)po);
        s_pk[i][1] = make_float4(gmh, e2p, b1, Lp);
    }
    __syncthreads();

    // ---- phase C: parity-split readlane gather, params pinned in VGPRs ----
    const int samp = t & 255;
    const int ks   = t >> 8;                  // parity: even / odd entries
    const int lane = t & 63;
    const int idx  = tile0 + samp;
    const float idxf = (float)idx;            // exact (<2^24)

    float4 A0 = s_pk[lane][0],      B0 = s_pk[lane][1];
    float4 A1 = make_float4(0.f, 0.f, 0.f, 0.f);
    float4 B1 = make_float4(0.f, 0.f, 0.f, -1.0e30f);
    float4 A2 = A1, B2 = B1;
    if (cnt > 64)  { A1 = s_pk[64 + lane][0];  B1 = s_pk[64 + lane][1]; }
    if (cnt > 128) { A2 = s_pk[128 + lane][0]; B2 = s_pk[128 + lane][1]; }

    // Opaque pin: compiler cannot rematerialize the LDS loads past an asm
    // that "writes" these values -> they stay resident in 24 VGPRs and the
    // loop below has ZERO memory operations.
    asm volatile("" : "+v"(A0.x), "+v"(A0.y), "+v"(A0.z), "+v"(A0.w),
                      "+v"(B0.x), "+v"(B0.y), "+v"(B0.z), "+v"(B0.w));
    asm volatile("" : "+v"(A1.x), "+v"(A1.y), "+v"(A1.z), "+v"(A1.w),
                      "+v"(B1.x), "+v"(B1.y), "+v"(B1.z), "+v"(B1.w));
    asm volatile("" : "+v"(A2.x), "+v"(A2.y), "+v"(A2.z), "+v"(A2.w),
                      "+v"(B2.x), "+v"(B2.y), "+v"(B2.z), "+v"(B2.w));

    float acc = 0.0f;
    int i = ks;                               // parity start, step 2
    #pragma unroll
    for (int c = 0; c < 3; ++c) {
        if (c * 64 < cnt) {
            const float4 A = (c == 0) ? A0 : (c == 1) ? A1 : A2;
            const float4 B = (c == 0) ? B0 : (c == 1) ? B1 : B2;
            const int end = min(cnt, (c + 1) << 6);
            for (; i < end; i += 2) {
                const int li = i & 63;
                // 8x v_readlane -> SGPRs; zero memory ops below
                float cf  = rl(A.x, li);
                float ohi = rl(A.y, li);
                float olo = rl(A.z, li);
                float po  = rl(A.w, li);
                float gmh = rl(B.x, li);
                float e2  = rl(B.y, li);
                float b1  = rl(B.z, li);
                float Lp  = rl(B.w, li);
                float kf  = idxf - cf;                 // exact, |k|<2^11
                float kf2 = kf * kf;
                float f1  = kf * ohi;                  // EXACT 11x12-bit product
                float p1  = __builtin_amdgcn_fractf(f1);   // exact fract
                p1 = fmaf(kf, olo, p1);                // + k*olo
                p1 = fmaf(gmh, kf2, p1);               // + chirp
                p1 += po;                              // + offset (sign folded)
                float mf = __builtin_amdgcn_fractf(p1);    // [0,1) revolutions
                float cz = __builtin_amdgcn_cosf(mf);  // cos(2*pi*mf)
                float ea = fmaf(e2, kf2, fmaf(b1, kf, Lp));
                float ev = __builtin_amdgcn_exp2f(ea); // |amp|*envelope
                acc = fmaf(ev, cz, acc);
            }
        }
    }

    if (ks == 0) s_part[samp] = acc;
    __syncthreads();
    if (ks == 1 && idx < num_samples) out[idx] = acc + s_part[samp];
}

// ---------------- fallback (n_atoms > 65535): proven round-3 scatter ----------------
__global__ __launch_bounds__(256)
void gabor_scatter(const float* __restrict__ amp, const float* __restrict__ tau,
                   const float* __restrict__ omg, const float* __restrict__ sig,
                   const float* __restrict__ phi, const float* __restrict__ gam,
                   float* __restrict__ out, int num_samples)
{
    const int atom = blockIdx.x;
    const float  a    = amp[atom];
    const double tu   = (double)tau[atom];
    const double om   = (double)omg[atom];
    const double sg   = (double)sig[atom];
    const double phr  = (double)phi[atom] * INV_2PI_D;
    const double gm_h = 0.5 * (double)gam[atom];
    const int center = (int)rint(tu * SR_D);
    const double sm = 5.0 * sg;
    const double inv_sg = 1.0 / sg;
    int hw = (int)ceil(sm * SR_D) + 1;
    hw = min(hw, HALF_MAX);
    int lo = max(center - hw, 0);
    int hi = min(center + hw, num_samples - 1);
    for (int idx = lo + (int)threadIdx.x; idx <= hi; idx += 256) {
        double t  = (double)idx * INV_SR_D;
        double dt = t - tu;
        if (fabs(dt) <= sm) {
            double z   = dt * inv_sg;
            float  env = __expf((float)(-0.5 * z * z));
            double r = om * dt + gm_h * dt * dt + phr;
            double f = r - floor(r);
            float  m = (float)f;
            float  c = __builtin_amdgcn_cosf(m);
            atomicAdd(&out[idx], a * env * c);
        }
    }
}

extern "C" void kernel_launch(void* const* d_in, const int* in_sizes, int n_in,
                              void* d_out, int out_size, void* d_ws, size_t ws_size,
                              hipStream_t stream)
{
    const float* amp = (const float*)d_in[0];
    const float* tau = (const float*)d_in[1];
    const float* omg = (const float*)d_in[2];
    const float* sig = (const float*)d_in[3];
    const float* phi = (const float*)d_in[4];
    const float* gam = (const float*)d_in[5];
    const int N = in_sizes[0];            // 16384 atoms
    float* out = (float*)d_out;

    if (N <= 65535) {
        const int n_tiles = (out_size + TILE - 1) >> 8;   // 938
        gabor_one<<<n_tiles, 512, 0, stream>>>(amp, tau, omg, sig, phi, gam,
                                               out, out_size, N);
    } else {
        hipMemsetAsync(out, 0, (size_t)out_size * sizeof(float), stream);
        gabor_scatter<<<N, 256, 0, stream>>>(amp, tau, omg, sig, phi, gam,
                                             out, out_size);
    }
}

// Round 13
// 88.869 us; speedup vs baseline: 1.1994x; 1.1994x over previous
//
#include <hip/hip_runtime.h>

// Gabor renderer, round 13.
// r9-r12 forensics: four different param-path formulations (global s_load,
// VGPR+readlane, LDS, LDS+asm-pin) all compile to the SAME canonical loop
// (uniform ds_read in-loop; VGPR 12-20, identical 38-43us phase C, identical
// counters r11==r12). The compiler wins. So optimize the canonical loop:
// phase C is latency-exposed (VALUBusy 50% @ 4 waves/SIMD, ~30cy exposed
// ds_read->lgkmcnt->use chain per eval vs ~24us overlapped issue floor).
// Fix: unroll x4 — each body issues 8 independent uniform ds_read_b128,
// THEN computes 4 evals (~104cy). One lgkmcnt wait per 4 evals, 8 loads in
// flight. List padded to a multiple of 8 with Lp=-1e30 sentinels (ev==0,
// exact zero contribution) -> no tail branch.
// Phases A/B + numerics unchanged from r11 (absmax 0.0234375 expected):
// k*ohi exact (12-bit ohi, |k|<2^11), v_fract exact, hw v_cos revolutions,
// exp2 envelope, amp sign folded as +0.5 rev.

constexpr double SR_D      = 24000.0;
constexpr double INV_SR_D  = 1.0 / 24000.0;
constexpr double INV_2PI_D = 0.15915494309189535;
constexpr double LOG2E_D   = 1.4426950408889634;
constexpr int    HALF_MAX  = 1201;
constexpr int    TILE      = 256;     // samples per tile
constexpr int    CAP       = 192;     // per-tile atom capacity (mean ~108, max ~160)

__global__ __launch_bounds__(512, 8)
void gabor_one(const float* __restrict__ amp, const float* __restrict__ tau,
               const float* __restrict__ omg, const float* __restrict__ sig,
               const float* __restrict__ phi, const float* __restrict__ gam,
               float* __restrict__ out, int num_samples, int n_atoms)
{
    __shared__ int            s_cnt;
    __shared__ unsigned short s_id[CAP];
    __shared__ float4         s_pk[CAP][2];
    __shared__ float          s_part[TILE];

    const int tile0 = blockIdx.x << 8;
    const int t     = (int)threadIdx.x;
    if (t == 0) s_cnt = 0;
    __syncthreads();

    // ---- phase A: conservative overlap scan (superset of |dt|<=5sig) ----
    const float lo_s = (float)(tile0 - 3);
    const float hi_s = (float)(tile0 + TILE - 1 + 3);
    for (int a = t; a < n_atoms; a += 512) {
        float c = tau[a] * 24000.0f;
        float w = fmaf(sig[a], 120000.0f, 2.0f);     // 5*sig*SR + margin
        if (c + w >= lo_s && c - w <= hi_s) {
            int slot = atomicAdd(&s_cnt, 1);
            if (slot < CAP) s_id[slot] = (unsigned short)a;
        }
    }
    __syncthreads();
    const int cnt     = min(s_cnt, CAP);
    const int cnt_pad = (cnt + 7) & ~7;              // multiple of 8, <= CAP

    // ---- phase B: f64 prep for listed atoms -> LDS packed params ----
    for (int i = t; i < cnt; i += 512) {
        int a = (int)s_id[i];
        double tu = (double)tau[a], om = (double)omg[a], gm = (double)gam[a];
        float  sgf = sig[a];
        float  amf = amp[a];
        int center = (int)rint(tu * SR_D);
        double q  = om * INV_SR_D;                       // [0, 1/3)
        float  qf = (float)q;
        float ohi = __uint_as_float(__float_as_uint(qf) & 0xFFFFF000u);
        float olo = (float)(q - (double)ohi);            // exact tail
        double d0 = (double)center * INV_SR_D - tu;      // f64: cancellation-safe
        double pr = om * d0 + (double)phi[a] * INV_2PI_D + 0.5 * gm * d0 * d0;
        double po = pr - floor(pr);
        if (amf < 0.0f) po += 0.5;                       // sign -> phase
        float isg2 = 1.0f / (sgf * sgf);                 // f32 IEEE div (~1e-7)
        double E2  = -0.5 * LOG2E_D * (double)isg2;      // exp2-domain coeff
        float e2p  = (float)(E2 * INV_SR_D * INV_SR_D);
        float b1   = (float)(2.0 * E2 * d0 * INV_SR_D);
        float aabs = fabsf(amf);
        float Lp   = (aabs > 0.0f)
                   ? __builtin_amdgcn_logf(aabs) + (float)(E2 * d0 * d0)
                   : -1.0e30f;                           // v_log_f32 = log2
        float gmh  = (float)(0.5 * gm * INV_SR_D * INV_SR_D);
        s_pk[i][0] = make_float4((float)center, ohi, olo, (float)po);
        s_pk[i][1] = make_float4(gmh, e2p, b1, Lp);
    }
    // sentinel padding: ev = exp2(-1e30) == 0 -> exact zero contribution
    for (int i = cnt + t; i < cnt_pad; i += 512) {
        s_pk[i][0] = make_float4(0.f, 0.f, 0.f, 0.f);
        s_pk[i][1] = make_float4(0.f, 0.f, 0.f, -1.0e30f);
    }
    __syncthreads();

    // ---- phase C: parity-split gather, 4 evals per lgkmcnt wait ----
    const int samp = t & 255;
    const int ks   = t >> 8;                  // parity: even / odd entries
    const int idx  = tile0 + samp;
    const float idxf = (float)idx;            // exact (<2^24)

    float acc = 0.0f;
    for (int i0 = ks; i0 < cnt_pad; i0 += 8) {
        // 8 independent uniform ds_read_b128, all issued before any use
        float4 a0 = s_pk[i0    ][0], b0 = s_pk[i0    ][1];
        float4 a1 = s_pk[i0 + 2][0], b1 = s_pk[i0 + 2][1];
        float4 a2 = s_pk[i0 + 4][0], b2 = s_pk[i0 + 4][1];
        float4 a3 = s_pk[i0 + 6][0], b3 = s_pk[i0 + 6][1];
        #pragma unroll
        for (int u = 0; u < 4; ++u) {
            const float4 A = (u == 0) ? a0 : (u == 1) ? a1 : (u == 2) ? a2 : a3;
            const float4 B = (u == 0) ? b0 : (u == 1) ? b1 : (u == 2) ? b2 : b3;
            float kf  = idxf - A.x;                    // exact, |k|<2^11
            float kf2 = kf * kf;
            float f1  = kf * A.y;                      // EXACT 11x12-bit product
            float p1  = __builtin_amdgcn_fractf(f1);   // exact fract
            p1 = fmaf(kf, A.z, p1);                    // + k*olo
            p1 = fmaf(B.x, kf2, p1);                   // + chirp
            p1 += A.w;                                 // + offset (sign folded)
            float mf = __builtin_amdgcn_fractf(p1);    // [0,1) revolutions
            float cz = __builtin_amdgcn_cosf(mf);      // cos(2*pi*mf)
            float ea = fmaf(B.y, kf2, fmaf(B.z, kf, B.w));
            float ev = __builtin_amdgcn_exp2f(ea);     // |amp|*envelope
            acc = fmaf(ev, cz, acc);
        }
    }

    if (ks == 0) s_part[samp] = acc;
    __syncthreads();
    if (ks == 1 && idx < num_samples) out[idx] = acc + s_part[samp];
}

// ---------------- fallback (n_atoms > 65535): proven round-3 scatter ----------------
__global__ __launch_bounds__(256)
void gabor_scatter(const float* __restrict__ amp, const float* __restrict__ tau,
                   const float* __restrict__ omg, const float* __restrict__ sig,
                   const float* __restrict__ phi, const float* __restrict__ gam,
                   float* __restrict__ out, int num_samples)
{
    const int atom = blockIdx.x;
    const float  a    = amp[atom];
    const double tu   = (double)tau[atom];
    const double om   = (double)omg[atom];
    const double sg   = (double)sig[atom];
    const double phr  = (double)phi[atom] * INV_2PI_D;
    const double gm_h = 0.5 * (double)gam[atom];
    const int center = (int)rint(tu * SR_D);
    const double sm = 5.0 * sg;
    const double inv_sg = 1.0 / sg;
    int hw = (int)ceil(sm * SR_D) + 1;
    hw = min(hw, HALF_MAX);
    int lo = max(center - hw, 0);
    int hi = min(center + hw, num_samples - 1);
    for (int idx = lo + (int)threadIdx.x; idx <= hi; idx += 256) {
        double t  = (double)idx * INV_SR_D;
        double dt = t - tu;
        if (fabs(dt) <= sm) {
            double z   = dt * inv_sg;
            float  env = __expf((float)(-0.5 * z * z));
            double r = om * dt + gm_h * dt * dt + phr;
            double f = r - floor(r);
            float  m = (float)f;
            float  c = __builtin_amdgcn_cosf(m);
            atomicAdd(&out[idx], a * env * c);
        }
    }
}

extern "C" void kernel_launch(void* const* d_in, const int* in_sizes, int n_in,
                              void* d_out, int out_size, void* d_ws, size_t ws_size,
                              hipStream_t stream)
{
    const float* amp = (const float*)d_in[0];
    const float* tau = (const float*)d_in[1];
    const float* omg = (const float*)d_in[2];
    const float* sig = (const float*)d_in[3];
    const float* phi = (const float*)d_in[4];
    const float* gam = (const float*)d_in[5];
    const int N = in_sizes[0];            // 16384 atoms
    float* out = (float*)d_out;

    if (N <= 65535) {
        const int n_tiles = (out_size + TILE - 1) >> 8;   // 938
        gabor_one<<<n_tiles, 512, 0, stream>>>(amp, tau, omg, sig, phi, gam,
                                               out, out_size, N);
    } else {
        hipMemsetAsync(out, 0, (size_t)out_size * sizeof(float), stream);
        gabor_scatter<<<N, 256, 0, stream>>>(amp, tau, omg, sig, phi, gam,
                                             out, out_size);
    }
}